// Round 6
// baseline (374.949 us; speedup 1.0000x reference)
//
#include <hip/hip_runtime.h>
#include <cstdint>
#include <cstddef>

typedef short short8 __attribute__((ext_vector_type(8)));
typedef float f32x4 __attribute__((ext_vector_type(4)));

#define LOG2E 1.44269504088896340736f
#define MASK_THR 2.44140625e-4f   // 2^-12 == 1/4096

__device__ inline unsigned short f2bf(float f) {
  unsigned int u = __float_as_uint(f);
  u += 0x7FFFu + ((u >> 16) & 1u);
  return (unsigned short)(u >> 16);
}
__device__ inline float bf2f(unsigned short s) {
  return __uint_as_float(((unsigned int)s) << 16);
}
__device__ inline void mfma16(f32x4 &acc, short8 a, short8 b) {
  asm volatile("v_mfma_f32_16x16x32_bf16 %0, %1, %2, %0"
               : "+v"(acc)
               : "v"(a), "v"(b));
}
__device__ inline void fence_after_mfma(f32x4 &x) {
  asm volatile("s_nop 7" : "+v"(x));
  asm volatile("s_nop 7" : "+v"(x));
}
__device__ inline void fence_before_mfma(f32x4 &x) {
  asm volatile("s_nop 1" : "+v"(x));
}
// VALU-write -> MFMA-read VGPR hazard fence (r5-proven necessity).
__device__ inline void fence_frag(short8 &x) {
  asm volatile("s_nop 7" : "+v"(x));
  asm volatile("s_nop 7" : "+v"(x));
}

// ---------------------------------------------------------------------------
// prep_w: split W into bf16 hi/lo MFMA A-fragments (r5-proven verbatim).
// ---------------------------------------------------------------------------
__global__ __launch_bounds__(256) void prep_w_kernel(
    const float* __restrict__ Wq, const float* __restrict__ Wk,
    const float* __restrict__ Wv,
    unsigned short* __restrict__ Wfh, unsigned short* __restrict__ Wfl)
{
  int id = blockIdx.x * 256 + threadIdx.x;   // 0..6143
  int li = id & 15, lg = (id >> 4) & 3, nt = (id >> 6) % 12, ch = id / 768;
  int n = nt * 16 + li;
  const float* W = (n < 64) ? Wq : ((n < 128) ? Wk : Wv);
  int col = n & 63;
  float sc = (n < 64) ? LOG2E : 1.0f;
  int k0 = ch * 32 + lg * 8;
  short8 hv, lv;
#pragma unroll
  for (int u = 0; u < 8; ++u) {
    float w = W[(k0 + u) * 64 + col] * sc;
    unsigned short h = f2bf(w);
    hv[u] = (short)h;
    lv[u] = (short)f2bf(w - bf2f(h));
  }
  *(short8*)(Wfh + (size_t)id * 8) = hv;
  *(short8*)(Wfl + (size_t)id * 8) = lv;
}

// ---------------------------------------------------------------------------
// proj (r5-proven verbatim): x @ Wf -> Qh/Ql, Kh/Kl, Vt.
// ---------------------------------------------------------------------------
__global__ __launch_bounds__(256) void proj_kernel(
    const float* __restrict__ x,
    const unsigned short* __restrict__ Wfh, const unsigned short* __restrict__ Wfl,
    const float* __restrict__ bq, const float* __restrict__ bk,
    const float* __restrict__ bv,
    unsigned short* __restrict__ Qh, unsigned short* __restrict__ Ql,
    unsigned short* __restrict__ Kh, unsigned short* __restrict__ Kl,
    unsigned short* __restrict__ Vt)
{
  __shared__ __align__(16) char sm[49408];
  const int t = threadIdx.x;
  const int wv = t >> 6, lane = t & 63, li = lane & 15, lg = lane >> 4;
  const int m0 = blockIdx.x * 64;

  f32x4 acc[12];
#pragma unroll
  for (int nt = 0; nt < 12; ++nt) { acc[nt] = (f32x4){0.f,0.f,0.f,0.f}; fence_before_mfma(acc[nt]); }

#pragma unroll 1
  for (int ch = 0; ch < 8; ++ch) {
    if (ch) __syncthreads();
#pragma unroll
    for (int i = 0; i < 3; ++i) {
      int sl = t + i * 256;
      *(uint4*)(sm + sl * 16)         = *(const uint4*)(Wfh + (size_t)ch * 6144 + sl * 8);
      *(uint4*)(sm + 12288 + sl * 16) = *(const uint4*)(Wfl + (size_t)ch * 6144 + sl * 8);
    }
    __syncthreads();
    const float* xp = x + (size_t)(m0 + wv * 16 + li) * 256 + ch * 32 + lg * 8;
    f32x4 xa = *(const f32x4*)xp;
    f32x4 xb = *(const f32x4*)(xp + 4);
    short8 xh, xl;
#pragma unroll
    for (int u = 0; u < 4; ++u) {
      unsigned short h = f2bf(xa[u]);
      xh[u] = (short)h; xl[u] = (short)f2bf(xa[u] - bf2f(h));
      unsigned short h2 = f2bf(xb[u]);
      xh[4 + u] = (short)h2; xl[4 + u] = (short)f2bf(xb[u] - bf2f(h2));
    }
    fence_frag(xh);
    fence_frag(xl);
#pragma unroll
    for (int nt = 0; nt < 12; ++nt) {
      short8 wh = *(const short8*)(sm + (nt * 64 + lg * 16 + li) * 16);
      short8 wl = *(const short8*)(sm + 12288 + (nt * 64 + lg * 16 + li) * 16);
      mfma16(acc[nt], wh, xh);
      mfma16(acc[nt], wh, xl);
      mfma16(acc[nt], wl, xh);
    }
  }
#pragma unroll
  for (int nt = 0; nt < 12; ++nt) fence_after_mfma(acc[nt]);
  __syncthreads();

  float* aL = (float*)(sm + wv * 12352);   // wave-private [16 rows][193 cols]
#pragma unroll
  for (int nt = 0; nt < 12; ++nt)
#pragma unroll
    for (int r = 0; r < 4; ++r)
      aL[li * 193 + nt * 16 + lg * 4 + r] = acc[nt][r];

  const int row = m0 + wv * 16 + li;
  const int b_idx = row >> 12, s0 = row & 4095;
  {
    unsigned int hq[8], lq[8];
#pragma unroll
    for (int c = 0; c < 16; c += 2) {
      float q0 = aL[li * 193 + lg * 16 + c]     + bq[lg * 16 + c] * LOG2E;
      float q1 = aL[li * 193 + lg * 16 + c + 1] + bq[lg * 16 + c + 1] * LOG2E;
      unsigned short h0 = f2bf(q0), h1 = f2bf(q1);
      hq[c >> 1] = (unsigned int)h0 | ((unsigned int)h1 << 16);
      lq[c >> 1] = (unsigned int)f2bf(q0 - bf2f(h0)) | ((unsigned int)f2bf(q1 - bf2f(h1)) << 16);
    }
    size_t o = (size_t)row * 64 + lg * 16;
    *(uint4*)(Qh + o)     = make_uint4(hq[0], hq[1], hq[2], hq[3]);
    *(uint4*)(Qh + o + 8) = make_uint4(hq[4], hq[5], hq[6], hq[7]);
    *(uint4*)(Ql + o)     = make_uint4(lq[0], lq[1], lq[2], lq[3]);
    *(uint4*)(Ql + o + 8) = make_uint4(lq[4], lq[5], lq[6], lq[7]);
  }
  {
    unsigned int hk[8], lk[8];
#pragma unroll
    for (int c = 0; c < 16; c += 2) {
      float k0 = aL[li * 193 + 64 + lg * 16 + c]     + bk[lg * 16 + c];
      float k1 = aL[li * 193 + 64 + lg * 16 + c + 1] + bk[lg * 16 + c + 1];
      unsigned short h0 = f2bf(k0), h1 = f2bf(k1);
      hk[c >> 1] = (unsigned int)h0 | ((unsigned int)h1 << 16);
      lk[c >> 1] = (unsigned int)f2bf(k0 - bf2f(h0)) | ((unsigned int)f2bf(k1 - bf2f(h1)) << 16);
    }
    size_t o = (size_t)row * 64 + lg * 16;
    *(uint4*)(Kh + o)     = make_uint4(hk[0], hk[1], hk[2], hk[3]);
    *(uint4*)(Kh + o + 8) = make_uint4(hk[4], hk[5], hk[6], hk[7]);
    *(uint4*)(Kl + o)     = make_uint4(lk[0], lk[1], lk[2], lk[3]);
    *(uint4*)(Kl + o + 8) = make_uint4(lk[4], lk[5], lk[6], lk[7]);
  }
#pragma unroll
  for (int c = 0; c < 16; ++c) {
    float vv = aL[li * 193 + 128 + lg * 16 + c] + bv[lg * 16 + c];
    Vt[((size_t)b_idx * 64 + lg * 16 + c) * 4096 + s0] = f2bf(vv);
  }
}

// ---------------------------------------------------------------------------
// attn_fused: two-pass flash, zero main-loop barriers.
// Grid 1024 (1-D, XCD-remapped: 2 XCDs per batch so per-XCD L2 holds one
// batch's K/Kl/Vt = 1.5MB). Block = 16 q-rows; 4 waves SPLIT J (disjoint
// interleaved j-tiles), K/V fragments global->reg (L2), Q + O in registers.
// Pass 1: per-row (m,z) -> shfl + LDS combine -> L. Pass 2: bit-identical
// score MFMAs, p=2^(s-L), mask p>2^-12, P via wave-private swizzled LDS
// (r5-proven pattern), PV accumulate; final cross-wave O reduce in LDS.
// LDS: P 4x2KB @0; obuf [4][16][68]f32 @8192 (17408B); smm/smz @25600.
// ---------------------------------------------------------------------------
#define P_OFF  0
#define OB_OFF 8192
#define SM_OFF 25600

__global__ __launch_bounds__(256) void attn_fused_kernel(
    const unsigned short* __restrict__ Qh, const unsigned short* __restrict__ Ql,
    const unsigned short* __restrict__ Kh, const unsigned short* __restrict__ Kl,
    const unsigned short* __restrict__ Vt,
    float* __restrict__ out)
{
  __shared__ __align__(16) char smc[26112];
  const int t = threadIdx.x;
  const int wv = t >> 6, lane = t & 63, li = lane & 15, lg = lane >> 4;

  // XCD-friendly remap: xcd = bid&7 (heuristic), 2 XCDs per batch.
  const int bid = blockIdx.x;
  const int xcd = bid & 7;
  const int b   = xcd >> 1;
  const int qt  = (bid >> 3) + ((xcd & 1) << 7);   // 0..255
  const int q0  = qt * 16;

  // Q fragments for the block's 16 rows (all waves identical; B-operand).
  short8 qh0, qh1, ql0, ql1;
  {
    size_t base = ((size_t)(b * 4096 + q0 + li)) * 64 + lg * 8;
    qh0 = *(const short8*)(Qh + base);
    qh1 = *(const short8*)(Qh + base + 32);
    ql0 = *(const short8*)(Ql + base);
    ql1 = *(const short8*)(Ql + base + 32);
  }
  const size_t kB = (size_t)b * 262144;

  // ===== pass 1: (m, z) per q-row over this wave's j-tiles =====
  float m = -3.0e38f, z = 0.0f;
#pragma unroll 1
  for (int i = 0; i < 16; ++i) {
    const int jt = i * 4 + wv;
#pragma unroll
    for (int s = 0; s < 4; ++s) {
      size_t ka = kB + (size_t)(jt * 64 + s * 16 + li) * 64 + lg * 8;
      short8 ah0 = *(const short8*)(Kh + ka);
      short8 ah1 = *(const short8*)(Kh + ka + 32);
      short8 al0 = *(const short8*)(Kl + ka);
      short8 al1 = *(const short8*)(Kl + ka + 32);
      f32x4 acc = {0.f, 0.f, 0.f, 0.f};
      fence_before_mfma(acc);
      mfma16(acc, ah0, qh0); mfma16(acc, ah0, ql0); mfma16(acc, al0, qh0);
      mfma16(acc, ah1, qh1); mfma16(acc, ah1, ql1); mfma16(acc, al1, qh1);
      fence_after_mfma(acc);
      float mx = fmaxf(fmaxf(acc[0], acc[1]), fmaxf(acc[2], acc[3]));
      float nm = fmaxf(m, mx);
      z = z * __builtin_exp2f(m - nm)
        + __builtin_exp2f(acc[0] - nm) + __builtin_exp2f(acc[1] - nm)
        + __builtin_exp2f(acc[2] - nm) + __builtin_exp2f(acc[3] - nm);
      m = nm;
    }
  }
  // combine the 4 lg-groups (same q=li, different j)
#pragma unroll
  for (int off = 16; off < 64; off <<= 1) {
    float om = __shfl_xor(m, off, 64);
    float oz = __shfl_xor(z, off, 64);
    float nm = fmaxf(m, om);
    z = z * __builtin_exp2f(m - nm) + oz * __builtin_exp2f(om - nm);
    m = nm;
  }
  // cross-wave combine via LDS
  float* smm = (float*)(smc + SM_OFF);
  float* smz = (float*)(smc + SM_OFF + 256);
  if (lane < 16) { smm[wv * 16 + lane] = m; smz[wv * 16 + lane] = z; }
  __syncthreads();
  float Lq;
  {
    float M = smm[li], Z = smz[li];
#pragma unroll
    for (int w2 = 1; w2 < 4; ++w2) {
      float om = smm[w2 * 16 + li], oz = smz[w2 * 16 + li];
      float nm = fmaxf(M, om);
      Z = Z * __builtin_exp2f(M - nm) + oz * __builtin_exp2f(om - nm);
      M = nm;
    }
    Lq = (Z > 0.0f) ? (M + __builtin_log2f(Z)) : M;
  }

  // ===== pass 2: masked PV over the same j-tiles =====
  f32x4 o0 = {0.f,0.f,0.f,0.f}, o1 = {0.f,0.f,0.f,0.f};
  f32x4 o2 = {0.f,0.f,0.f,0.f}, o3 = {0.f,0.f,0.f,0.f};
  fence_before_mfma(o0); fence_before_mfma(o1);
  fence_before_mfma(o2); fence_before_mfma(o3);

  const int sw = li & 7;
  const int pbase  = P_OFF + wv * 2048 + li * 128;
  const int pwslot = (lg & 1) * 8;
  const int slotA0 = ((lg)     ^ sw) << 4;
  const int slotA1 = ((4 + lg) ^ sw) << 4;

#pragma unroll 1
  for (int i = 0; i < 16; ++i) {
    const int jt = i * 4 + wv;
    // scores -> masked P into wave-private swizzled LDS (r5-proven pattern)
#pragma unroll
    for (int s = 0; s < 4; ++s) {
      size_t ka = kB + (size_t)(jt * 64 + s * 16 + li) * 64 + lg * 8;
      short8 ah0 = *(const short8*)(Kh + ka);
      short8 ah1 = *(const short8*)(Kh + ka + 32);
      short8 al0 = *(const short8*)(Kl + ka);
      short8 al1 = *(const short8*)(Kl + ka + 32);
      f32x4 acc = {0.f, 0.f, 0.f, 0.f};
      fence_before_mfma(acc);
      mfma16(acc, ah0, qh0); mfma16(acc, ah0, ql0); mfma16(acc, al0, qh0);
      mfma16(acc, ah1, qh1); mfma16(acc, ah1, ql1); mfma16(acc, al1, qh1);
      fence_after_mfma(acc);
      float p0 = __builtin_exp2f(acc[0] - Lq); p0 = (p0 > MASK_THR) ? p0 : 0.0f;
      float p1 = __builtin_exp2f(acc[1] - Lq); p1 = (p1 > MASK_THR) ? p1 : 0.0f;
      float p2 = __builtin_exp2f(acc[2] - Lq); p2 = (p2 > MASK_THR) ? p2 : 0.0f;
      float p3 = __builtin_exp2f(acc[3] - Lq); p3 = (p3 > MASK_THR) ? p3 : 0.0f;
      uint2 pw;
      pw.x = (unsigned int)f2bf(p0) | ((unsigned int)f2bf(p1) << 16);
      pw.y = (unsigned int)f2bf(p2) | ((unsigned int)f2bf(p3) << 16);
      *(uint2*)(smc + pbase + (((2 * s + (lg >> 1)) ^ sw) << 4) + pwslot) = pw;
    }
    short8 pa0 = *(const short8*)(smc + pbase + slotA0);
    short8 pa1 = *(const short8*)(smc + pbase + slotA1);
    // PV: V fragments direct from global (B-operand), d-groups 0..3
    {
      size_t va = ((size_t)b * 64 + li) * 4096 + jt * 64 + lg * 8;
      short8 vb0 = *(const short8*)(Vt + va);
      short8 vb1 = *(const short8*)(Vt + va + 32);
      mfma16(o0, pa0, vb0); mfma16(o0, pa1, vb1);
      vb0 = *(const short8*)(Vt + va + 16 * 4096);
      vb1 = *(const short8*)(Vt + va + 16 * 4096 + 32);
      mfma16(o1, pa0, vb0); mfma16(o1, pa1, vb1);
      vb0 = *(const short8*)(Vt + va + 32 * 4096);
      vb1 = *(const short8*)(Vt + va + 32 * 4096 + 32);
      mfma16(o2, pa0, vb0); mfma16(o2, pa1, vb1);
      vb0 = *(const short8*)(Vt + va + 48 * 4096);
      vb1 = *(const short8*)(Vt + va + 48 * 4096 + 32);
      mfma16(o3, pa0, vb0); mfma16(o3, pa1, vb1);
    }
  }
  fence_after_mfma(o0); fence_after_mfma(o1);
  fence_after_mfma(o2); fence_after_mfma(o3);

  // cross-wave O reduction: obuf[wv][16 q][68 pad] f32
  float* ob = (float*)(smc + OB_OFF);
#pragma unroll
  for (int r = 0; r < 4; ++r) {
    ob[(wv * 16 + lg * 4 + r) * 68 +  0 + li] = o0[r];
    ob[(wv * 16 + lg * 4 + r) * 68 + 16 + li] = o1[r];
    ob[(wv * 16 + lg * 4 + r) * 68 + 32 + li] = o2[r];
    ob[(wv * 16 + lg * 4 + r) * 68 + 48 + li] = o3[r];
  }
  __syncthreads();
  {
    const int q = t >> 4, dg = t & 15;
    f32x4 s4 = *(const f32x4*)(ob + q * 68 + dg * 4);
    s4 += *(const f32x4*)(ob + (16 + q) * 68 + dg * 4);
    s4 += *(const f32x4*)(ob + (32 + q) * 68 + dg * 4);
    s4 += *(const f32x4*)(ob + (48 + q) * 68 + dg * 4);
    *(f32x4*)(out + ((size_t)b * 4096 + q0 + q) * 64 + dg * 4) = s4;
  }
}

extern "C" void kernel_launch(void* const* d_in, const int* in_sizes, int n_in,
                              void* d_out, int out_size, void* d_ws, size_t ws_size,
                              hipStream_t stream) {
  (void)in_sizes; (void)n_in; (void)out_size; (void)ws_size;
  const float* x  = (const float*)d_in[0];
  const float* Wq = (const float*)d_in[1];
  const float* bq = (const float*)d_in[2];
  const float* Wk = (const float*)d_in[3];
  const float* bk = (const float*)d_in[4];
  const float* Wv = (const float*)d_in[5];
  const float* bv = (const float*)d_in[6];
  float* out = (float*)d_out;

  char* wsb = (char*)d_ws;
  unsigned short* Qh  = (unsigned short*)(wsb);
  unsigned short* Ql  = (unsigned short*)(wsb + 2097152);
  unsigned short* Kh  = (unsigned short*)(wsb + 4194304);
  unsigned short* Kl  = (unsigned short*)(wsb + 6291456);
  unsigned short* Vt  = (unsigned short*)(wsb + 8388608);
  unsigned short* Wfh = (unsigned short*)(wsb + 10485760);
  unsigned short* Wfl = (unsigned short*)(wsb + 10584064);

  prep_w_kernel<<<dim3(24), dim3(256), 0, stream>>>(Wq, Wk, Wv, Wfh, Wfl);
  proj_kernel<<<dim3(256), dim3(256), 0, stream>>>(
      x, Wfh, Wfl, bq, bk, bv, Qh, Ql, Kh, Kl, Vt);
  attn_fused_kernel<<<dim3(1024), dim3(256), 0, stream>>>(
      Qh, Ql, Kh, Kl, Vt, out);
}

// Round 7
// 321.217 us; speedup vs baseline: 1.1673x; 1.1673x over previous
//
#include <hip/hip_runtime.h>
#include <cstdint>
#include <cstddef>

typedef short short8 __attribute__((ext_vector_type(8)));
typedef float f32x4 __attribute__((ext_vector_type(4)));

#define LOG2E 1.44269504088896340736f
#define MASK_THR 2.44140625e-4f   // 2^-12 == 1/4096

__device__ inline unsigned short f2bf(float f) {
  unsigned int u = __float_as_uint(f);
  u += 0x7FFFu + ((u >> 16) & 1u);
  return (unsigned short)(u >> 16);
}
__device__ inline float bf2f(unsigned short s) {
  return __uint_as_float(((unsigned int)s) << 16);
}
__device__ inline void mfma16(f32x4 &acc, short8 a, short8 b) {
  asm volatile("v_mfma_f32_16x16x32_bf16 %0, %1, %2, %0"
               : "+v"(acc)
               : "v"(a), "v"(b));
}
__device__ inline void fence_after_mfma(f32x4 &x) {
  asm volatile("s_nop 7" : "+v"(x));
  asm volatile("s_nop 7" : "+v"(x));
}
__device__ inline void fence_before_mfma(f32x4 &x) {
  asm volatile("s_nop 1" : "+v"(x));
}
// VALU-write -> MFMA-read VGPR hazard fence (r5-proven necessity).
__device__ inline void fence_frag(short8 &x) {
  asm volatile("s_nop 7" : "+v"(x));
  asm volatile("s_nop 7" : "+v"(x));
}

// ---------------------------------------------------------------------------
// prep_w: split W into bf16 hi/lo MFMA A-fragments (r5-proven verbatim).
// ---------------------------------------------------------------------------
__global__ __launch_bounds__(256) void prep_w_kernel(
    const float* __restrict__ Wq, const float* __restrict__ Wk,
    const float* __restrict__ Wv,
    unsigned short* __restrict__ Wfh, unsigned short* __restrict__ Wfl)
{
  int id = blockIdx.x * 256 + threadIdx.x;   // 0..6143
  int li = id & 15, lg = (id >> 4) & 3, nt = (id >> 6) % 12, ch = id / 768;
  int n = nt * 16 + li;
  const float* W = (n < 64) ? Wq : ((n < 128) ? Wk : Wv);
  int col = n & 63;
  float sc = (n < 64) ? LOG2E : 1.0f;
  int k0 = ch * 32 + lg * 8;
  short8 hv, lv;
#pragma unroll
  for (int u = 0; u < 8; ++u) {
    float w = W[(k0 + u) * 64 + col] * sc;
    unsigned short h = f2bf(w);
    hv[u] = (short)h;
    lv[u] = (short)f2bf(w - bf2f(h));
  }
  *(short8*)(Wfh + (size_t)id * 8) = hv;
  *(short8*)(Wfl + (size_t)id * 8) = lv;
}

// ---------------------------------------------------------------------------
// proj (r5-proven verbatim): x @ Wf -> Qh/Ql, Kh/Kl, Vt.
// ---------------------------------------------------------------------------
__global__ __launch_bounds__(256) void proj_kernel(
    const float* __restrict__ x,
    const unsigned short* __restrict__ Wfh, const unsigned short* __restrict__ Wfl,
    const float* __restrict__ bq, const float* __restrict__ bk,
    const float* __restrict__ bv,
    unsigned short* __restrict__ Qh, unsigned short* __restrict__ Ql,
    unsigned short* __restrict__ Kh, unsigned short* __restrict__ Kl,
    unsigned short* __restrict__ Vt)
{
  __shared__ __align__(16) char sm[49408];
  const int t = threadIdx.x;
  const int wv = t >> 6, lane = t & 63, li = lane & 15, lg = lane >> 4;
  const int m0 = blockIdx.x * 64;

  f32x4 acc[12];
#pragma unroll
  for (int nt = 0; nt < 12; ++nt) { acc[nt] = (f32x4){0.f,0.f,0.f,0.f}; fence_before_mfma(acc[nt]); }

#pragma unroll 1
  for (int ch = 0; ch < 8; ++ch) {
    if (ch) __syncthreads();
#pragma unroll
    for (int i = 0; i < 3; ++i) {
      int sl = t + i * 256;
      *(uint4*)(sm + sl * 16)         = *(const uint4*)(Wfh + (size_t)ch * 6144 + sl * 8);
      *(uint4*)(sm + 12288 + sl * 16) = *(const uint4*)(Wfl + (size_t)ch * 6144 + sl * 8);
    }
    __syncthreads();
    const float* xp = x + (size_t)(m0 + wv * 16 + li) * 256 + ch * 32 + lg * 8;
    f32x4 xa = *(const f32x4*)xp;
    f32x4 xb = *(const f32x4*)(xp + 4);
    short8 xh, xl;
#pragma unroll
    for (int u = 0; u < 4; ++u) {
      unsigned short h = f2bf(xa[u]);
      xh[u] = (short)h; xl[u] = (short)f2bf(xa[u] - bf2f(h));
      unsigned short h2 = f2bf(xb[u]);
      xh[4 + u] = (short)h2; xl[4 + u] = (short)f2bf(xb[u] - bf2f(h2));
    }
    fence_frag(xh);
    fence_frag(xl);
#pragma unroll
    for (int nt = 0; nt < 12; ++nt) {
      short8 wh = *(const short8*)(sm + (nt * 64 + lg * 16 + li) * 16);
      short8 wl = *(const short8*)(sm + 12288 + (nt * 64 + lg * 16 + li) * 16);
      mfma16(acc[nt], wh, xh);
      mfma16(acc[nt], wh, xl);
      mfma16(acc[nt], wl, xh);
    }
  }
#pragma unroll
  for (int nt = 0; nt < 12; ++nt) fence_after_mfma(acc[nt]);
  __syncthreads();

  float* aL = (float*)(sm + wv * 12352);   // wave-private [16 rows][193 cols]
#pragma unroll
  for (int nt = 0; nt < 12; ++nt)
#pragma unroll
    for (int r = 0; r < 4; ++r)
      aL[li * 193 + nt * 16 + lg * 4 + r] = acc[nt][r];

  const int row = m0 + wv * 16 + li;
  const int b_idx = row >> 12, s0 = row & 4095;
  {
    unsigned int hq[8], lq[8];
#pragma unroll
    for (int c = 0; c < 16; c += 2) {
      float q0 = aL[li * 193 + lg * 16 + c]     + bq[lg * 16 + c] * LOG2E;
      float q1 = aL[li * 193 + lg * 16 + c + 1] + bq[lg * 16 + c + 1] * LOG2E;
      unsigned short h0 = f2bf(q0), h1 = f2bf(q1);
      hq[c >> 1] = (unsigned int)h0 | ((unsigned int)h1 << 16);
      lq[c >> 1] = (unsigned int)f2bf(q0 - bf2f(h0)) | ((unsigned int)f2bf(q1 - bf2f(h1)) << 16);
    }
    size_t o = (size_t)row * 64 + lg * 16;
    *(uint4*)(Qh + o)     = make_uint4(hq[0], hq[1], hq[2], hq[3]);
    *(uint4*)(Qh + o + 8) = make_uint4(hq[4], hq[5], hq[6], hq[7]);
    *(uint4*)(Ql + o)     = make_uint4(lq[0], lq[1], lq[2], lq[3]);
    *(uint4*)(Ql + o + 8) = make_uint4(lq[4], lq[5], lq[6], lq[7]);
  }
  {
    unsigned int hk[8], lk[8];
#pragma unroll
    for (int c = 0; c < 16; c += 2) {
      float k0 = aL[li * 193 + 64 + lg * 16 + c]     + bk[lg * 16 + c];
      float k1 = aL[li * 193 + 64 + lg * 16 + c + 1] + bk[lg * 16 + c + 1];
      unsigned short h0 = f2bf(k0), h1 = f2bf(k1);
      hk[c >> 1] = (unsigned int)h0 | ((unsigned int)h1 << 16);
      lk[c >> 1] = (unsigned int)f2bf(k0 - bf2f(h0)) | ((unsigned int)f2bf(k1 - bf2f(h1)) << 16);
    }
    size_t o = (size_t)row * 64 + lg * 16;
    *(uint4*)(Kh + o)     = make_uint4(hk[0], hk[1], hk[2], hk[3]);
    *(uint4*)(Kh + o + 8) = make_uint4(hk[4], hk[5], hk[6], hk[7]);
    *(uint4*)(Kl + o)     = make_uint4(lk[0], lk[1], lk[2], lk[3]);
    *(uint4*)(Kl + o + 8) = make_uint4(lk[4], lk[5], lk[6], lk[7]);
  }
#pragma unroll
  for (int c = 0; c < 16; ++c) {
    float vv = aL[li * 193 + 128 + lg * 16 + c] + bv[lg * 16 + c];
    Vt[((size_t)b_idx * 64 + lg * 16 + c) * 4096 + s0] = f2bf(vv);
  }
}

// ---------------------------------------------------------------------------
// stats: full-j per block. Grid 256 (XCD-mapped: 2 XCDs/batch). 4 waves
// q-split (16 rows each, r5-proven inner). Single-barrier dbuf staging:
// per tile: write prefetched regs -> buf^1, issue loads(t+2), compute buf^0,
// barrier. Writes L = M + log2(Z) directly (no partials/combine).
// LDS: 2 x (Kh 8K | Kl 8K) = 32KB.
// ---------------------------------------------------------------------------
__global__ __launch_bounds__(256) void stats_kernel(
    const unsigned short* __restrict__ Qh, const unsigned short* __restrict__ Ql,
    const unsigned short* __restrict__ Kh, const unsigned short* __restrict__ Kl,
    float* __restrict__ Lrow)
{
  __shared__ __align__(16) char sm[32768];
  const int t = threadIdx.x;
  const int wv = t >> 6, lane = t & 63, li = lane & 15, lg = lane >> 4;
  const int bid = blockIdx.x, g = bid & 7;
  const int b  = g >> 1;                        // 2 XCDs per batch
  const int qt = ((bid >> 3) << 1) | (g & 1);   // 0..63
  const int q0 = qt * 64 + wv * 16;
  const int sw = li & 7;
  const int slotA0 = ((lg)     ^ sw) << 4;
  const int slotA1 = ((4 + lg) ^ sw) << 4;

  short8 qh0, qh1, ql0, ql1;
  {
    size_t base = ((size_t)(b * 4096 + q0 + li)) * 64 + lg * 8;
    qh0 = *(const short8*)(Qh + base);
    qh1 = *(const short8*)(Qh + base + 32);
    ql0 = *(const short8*)(Ql + base);
    ql1 = *(const short8*)(Ql + base + 32);
  }
  int sls[2] = { t, t + 256 };
  int st_off[2];
#pragma unroll
  for (int i = 0; i < 2; ++i) {
    int row = sls[i] >> 3, k16 = sls[i] & 7;
    st_off[i] = row * 128 + ((k16 ^ (row & 7)) << 4);
  }
  const size_t kbase = (size_t)b * 262144;

  uint4 rkh[2], rkl[2];
#define LOADK(jt_) do { \
    _Pragma("unroll") for (int i = 0; i < 2; ++i) { \
      rkh[i] = *(const uint4*)(Kh + kbase + (size_t)(jt_) * 4096 + sls[i] * 8); \
      rkl[i] = *(const uint4*)(Kl + kbase + (size_t)(jt_) * 4096 + sls[i] * 8); \
    } } while (0)
#define WRITEK(bw_) do { \
    _Pragma("unroll") for (int i = 0; i < 2; ++i) { \
      *(uint4*)((bw_) + st_off[i])        = rkh[i]; \
      *(uint4*)((bw_) + 8192 + st_off[i]) = rkl[i]; \
    } } while (0)

  LOADK(0);
  WRITEK(sm);
  LOADK(1);
  __syncthreads();

  float m = -3.0e38f, z = 0.0f;
#pragma unroll 1
  for (int jt = 0; jt < 64; ++jt) {
    char* bR = sm + (jt & 1) * 16384;
    char* bW = sm + ((jt & 1) ^ 1) * 16384;
    if (jt < 63) {
      WRITEK(bW);
      if (jt < 62) LOADK(jt + 2);
    }
#pragma unroll
    for (int s = 0; s < 4; ++s) {
      f32x4 acc = {0.f, 0.f, 0.f, 0.f};
      fence_before_mfma(acc);
      const int rowb = (16 * s + li) * 128;
      short8 ah0 = *(const short8*)(bR + rowb + slotA0);
      short8 al0 = *(const short8*)(bR + 8192 + rowb + slotA0);
      short8 ah1 = *(const short8*)(bR + rowb + slotA1);
      short8 al1 = *(const short8*)(bR + 8192 + rowb + slotA1);
      mfma16(acc, ah0, qh0); mfma16(acc, ah0, ql0); mfma16(acc, al0, qh0);
      mfma16(acc, ah1, qh1); mfma16(acc, ah1, ql1); mfma16(acc, al1, qh1);
      fence_after_mfma(acc);
      float mx = fmaxf(fmaxf(acc[0], acc[1]), fmaxf(acc[2], acc[3]));
      float nm = fmaxf(m, mx);
      z = z * __builtin_exp2f(m - nm)
        + __builtin_exp2f(acc[0] - nm) + __builtin_exp2f(acc[1] - nm)
        + __builtin_exp2f(acc[2] - nm) + __builtin_exp2f(acc[3] - nm);
      m = nm;
    }
    __syncthreads();
  }
#undef LOADK
#undef WRITEK
#pragma unroll
  for (int off = 16; off < 64; off <<= 1) {
    float om = __shfl_xor(m, off, 64);
    float oz = __shfl_xor(z, off, 64);
    float nm = fmaxf(m, om);
    z = z * __builtin_exp2f(m - nm) + oz * __builtin_exp2f(om - nm);
    m = nm;
  }
  if (lane < 16) {
    float L = (z > 0.0f) ? (m + __builtin_log2f(z)) : m;
    Lrow[b * 4096 + q0 + lane] = L;
  }
}

// ---------------------------------------------------------------------------
// pv: full-j per block, plain stores (no atomics). Grid 256 (XCD-mapped).
// r5-proven inner compute (scores, mask p=2^(s-L)>2^-12, P via wave-private
// swizzled LDS, PV MFMA). Single-barrier dbuf staging of Kh/Kl/Vt.
// LDS: 2 x (Kh 8K | Kl 8K | Vt 8K) = 48KB @0; P 4x2KB @49152.
// ---------------------------------------------------------------------------
__global__ __launch_bounds__(256) void pv_kernel(
    const unsigned short* __restrict__ Qh, const unsigned short* __restrict__ Ql,
    const unsigned short* __restrict__ Kh, const unsigned short* __restrict__ Kl,
    const unsigned short* __restrict__ Vt, const float* __restrict__ Lrow,
    float* __restrict__ out)
{
  __shared__ __align__(16) char sm[57344];
  const int t = threadIdx.x;
  const int wv = t >> 6, lane = t & 63, li = lane & 15, lg = lane >> 4;
  const int bid = blockIdx.x, g = bid & 7;
  const int b  = g >> 1;
  const int qt = ((bid >> 3) << 1) | (g & 1);
  const int q0 = qt * 64 + wv * 16;
  const int sw = li & 7;
  const int slotA0 = ((lg)     ^ sw) << 4;
  const int slotA1 = ((4 + lg) ^ sw) << 4;

  short8 qh0, qh1, ql0, ql1;
  {
    size_t base = ((size_t)(b * 4096 + q0 + li)) * 64 + lg * 8;
    qh0 = *(const short8*)(Qh + base);
    qh1 = *(const short8*)(Qh + base + 32);
    ql0 = *(const short8*)(Ql + base);
    ql1 = *(const short8*)(Ql + base + 32);
  }
  const float L = Lrow[b * 4096 + q0 + li];

  int sls[2] = { t, t + 256 };
  int st_off[2];
#pragma unroll
  for (int i = 0; i < 2; ++i) {
    int row = sls[i] >> 3, k16 = sls[i] & 7;
    st_off[i] = row * 128 + ((k16 ^ (row & 7)) << 4);
  }
  const size_t kbase = (size_t)b * 262144;

  uint4 rkh[2], rkl[2], rvt[2];
#define LOADKV(jt_) do { \
    _Pragma("unroll") for (int i = 0; i < 2; ++i) { \
      rkh[i] = *(const uint4*)(Kh + kbase + (size_t)(jt_) * 4096 + sls[i] * 8); \
      rkl[i] = *(const uint4*)(Kl + kbase + (size_t)(jt_) * 4096 + sls[i] * 8); \
      rvt[i] = *(const uint4*)(Vt + ((size_t)b * 64 + (sls[i] >> 3)) * 4096 \
                               + (size_t)(jt_) * 64 + (sls[i] & 7) * 8); \
    } } while (0)
#define WRITEKV(bw_) do { \
    _Pragma("unroll") for (int i = 0; i < 2; ++i) { \
      *(uint4*)((bw_) + st_off[i])         = rkh[i]; \
      *(uint4*)((bw_) + 8192  + st_off[i]) = rkl[i]; \
      *(uint4*)((bw_) + 16384 + st_off[i]) = rvt[i]; \
    } } while (0)

  LOADKV(0);
  WRITEKV(sm);
  LOADKV(1);
  __syncthreads();

  f32x4 o0 = {0.f,0.f,0.f,0.f}, o1 = {0.f,0.f,0.f,0.f};
  f32x4 o2 = {0.f,0.f,0.f,0.f}, o3 = {0.f,0.f,0.f,0.f};
  fence_before_mfma(o0); fence_before_mfma(o1);
  fence_before_mfma(o2); fence_before_mfma(o3);

  const int pbase  = 49152 + wv * 2048 + li * 128;
  const int pwslot = (lg & 1) * 8;

#pragma unroll 1
  for (int jt = 0; jt < 64; ++jt) {
    char* bR = sm + (jt & 1) * 24576;
    char* bW = sm + ((jt & 1) ^ 1) * 24576;
    if (jt < 63) {
      WRITEKV(bW);
      if (jt < 62) LOADKV(jt + 2);
    }
    // scores -> masked P into wave-private swizzled LDS (r5-proven)
#pragma unroll
    for (int s = 0; s < 4; ++s) {
      f32x4 acc = {0.f, 0.f, 0.f, 0.f};
      fence_before_mfma(acc);
      const int rowb = (16 * s + li) * 128;
      short8 ah0 = *(const short8*)(bR + rowb + slotA0);
      short8 al0 = *(const short8*)(bR + 8192 + rowb + slotA0);
      short8 ah1 = *(const short8*)(bR + rowb + slotA1);
      short8 al1 = *(const short8*)(bR + 8192 + rowb + slotA1);
      mfma16(acc, ah0, qh0); mfma16(acc, ah0, ql0); mfma16(acc, al0, qh0);
      mfma16(acc, ah1, qh1); mfma16(acc, ah1, ql1); mfma16(acc, al1, qh1);
      fence_after_mfma(acc);
      float p0 = __builtin_exp2f(acc[0] - L); p0 = (p0 > MASK_THR) ? p0 : 0.0f;
      float p1 = __builtin_exp2f(acc[1] - L); p1 = (p1 > MASK_THR) ? p1 : 0.0f;
      float p2 = __builtin_exp2f(acc[2] - L); p2 = (p2 > MASK_THR) ? p2 : 0.0f;
      float p3 = __builtin_exp2f(acc[3] - L); p3 = (p3 > MASK_THR) ? p3 : 0.0f;
      uint2 pw;
      pw.x = (unsigned int)f2bf(p0) | ((unsigned int)f2bf(p1) << 16);
      pw.y = (unsigned int)f2bf(p2) | ((unsigned int)f2bf(p3) << 16);
      *(uint2*)(sm + pbase + (((2 * s + (lg >> 1)) ^ sw) << 4) + pwslot) = pw;
    }
    short8 pa0 = *(const short8*)(sm + pbase + slotA0);
    short8 pa1 = *(const short8*)(sm + pbase + slotA1);
    {
      short8 vb0 = *(const short8*)(bR + 16384 + (li) * 128 + slotA0);
      short8 vb1 = *(const short8*)(bR + 16384 + (li) * 128 + slotA1);
      mfma16(o0, pa0, vb0); mfma16(o0, pa1, vb1);
      vb0 = *(const short8*)(bR + 16384 + (16 + li) * 128 + slotA0);
      vb1 = *(const short8*)(bR + 16384 + (16 + li) * 128 + slotA1);
      mfma16(o1, pa0, vb0); mfma16(o1, pa1, vb1);
      vb0 = *(const short8*)(bR + 16384 + (32 + li) * 128 + slotA0);
      vb1 = *(const short8*)(bR + 16384 + (32 + li) * 128 + slotA1);
      mfma16(o2, pa0, vb0); mfma16(o2, pa1, vb1);
      vb0 = *(const short8*)(bR + 16384 + (48 + li) * 128 + slotA0);
      vb1 = *(const short8*)(bR + 16384 + (48 + li) * 128 + slotA1);
      mfma16(o3, pa0, vb0); mfma16(o3, pa1, vb1);
    }
    __syncthreads();
  }
#undef LOADKV
#undef WRITEKV
  fence_after_mfma(o0); fence_after_mfma(o1);
  fence_after_mfma(o2); fence_after_mfma(o3);

  const size_t ob = ((size_t)b * 4096 + q0) * 64;
#pragma unroll
  for (int r = 0; r < 4; ++r) {
    size_t rowoff = ob + (size_t)(lg * 4 + r) * 64 + li;
    out[rowoff]      = o0[r];
    out[rowoff + 16] = o1[r];
    out[rowoff + 32] = o2[r];
    out[rowoff + 48] = o3[r];
  }
}

extern "C" void kernel_launch(void* const* d_in, const int* in_sizes, int n_in,
                              void* d_out, int out_size, void* d_ws, size_t ws_size,
                              hipStream_t stream) {
  (void)in_sizes; (void)n_in; (void)out_size; (void)ws_size;
  const float* x  = (const float*)d_in[0];
  const float* Wq = (const float*)d_in[1];
  const float* bq = (const float*)d_in[2];
  const float* Wk = (const float*)d_in[3];
  const float* bk = (const float*)d_in[4];
  const float* Wv = (const float*)d_in[5];
  const float* bv = (const float*)d_in[6];
  float* out = (float*)d_out;

  char* wsb = (char*)d_ws;
  unsigned short* Qh  = (unsigned short*)(wsb);
  unsigned short* Ql  = (unsigned short*)(wsb + 2097152);
  unsigned short* Kh  = (unsigned short*)(wsb + 4194304);
  unsigned short* Kl  = (unsigned short*)(wsb + 6291456);
  unsigned short* Vt  = (unsigned short*)(wsb + 8388608);
  unsigned short* Wfh = (unsigned short*)(wsb + 10485760);
  unsigned short* Wfl = (unsigned short*)(wsb + 10584064);
  float*         Lrow = (float*)(wsb + 10682368);  // 64KB

  prep_w_kernel<<<dim3(24), dim3(256), 0, stream>>>(Wq, Wk, Wv, Wfh, Wfl);
  proj_kernel<<<dim3(256), dim3(256), 0, stream>>>(
      x, Wfh, Wfl, bq, bk, bv, Qh, Ql, Kh, Kl, Vt);
  stats_kernel<<<dim3(256), dim3(256), 0, stream>>>(Qh, Ql, Kh, Kl, Lrow);
  pv_kernel<<<dim3(256), dim3(256), 0, stream>>>(Qh, Ql, Kh, Kl, Vt, Lrow, out);
}

// Round 8
// 235.034 us; speedup vs baseline: 1.5953x; 1.3667x over previous
//
#include <hip/hip_runtime.h>
#include <cstdint>
#include <cstddef>

typedef short short8 __attribute__((ext_vector_type(8)));
typedef float f32x4 __attribute__((ext_vector_type(4)));

#define LOG2E 1.44269504088896340736f
#define MASK_THR 2.44140625e-4f   // 2^-12 == 1/4096

__device__ inline unsigned short f2bf(float f) {
  unsigned int u = __float_as_uint(f);
  u += 0x7FFFu + ((u >> 16) & 1u);
  return (unsigned short)(u >> 16);
}
__device__ inline float bf2f(unsigned short s) {
  return __uint_as_float(((unsigned int)s) << 16);
}
__device__ inline void mfma16(f32x4 &acc, short8 a, short8 b) {
  asm volatile("v_mfma_f32_16x16x32_bf16 %0, %1, %2, %0"
               : "+v"(acc)
               : "v"(a), "v"(b));
}
__device__ inline void fence_after_mfma(f32x4 &x) {
  asm volatile("s_nop 7" : "+v"(x));
  asm volatile("s_nop 7" : "+v"(x));
}
__device__ inline void fence_before_mfma(f32x4 &x) {
  asm volatile("s_nop 1" : "+v"(x));
}
// VALU-write -> MFMA-read VGPR hazard fence (r5-proven necessity).
__device__ inline void fence_frag(short8 &x) {
  asm volatile("s_nop 7" : "+v"(x));
  asm volatile("s_nop 7" : "+v"(x));
}

// ---------------------------------------------------------------------------
// prep_w: split W into bf16 hi/lo MFMA A-fragments (r5-proven verbatim).
// ---------------------------------------------------------------------------
__global__ __launch_bounds__(256) void prep_w_kernel(
    const float* __restrict__ Wq, const float* __restrict__ Wk,
    const float* __restrict__ Wv,
    unsigned short* __restrict__ Wfh, unsigned short* __restrict__ Wfl)
{
  int id = blockIdx.x * 256 + threadIdx.x;   // 0..6143
  int li = id & 15, lg = (id >> 4) & 3, nt = (id >> 6) % 12, ch = id / 768;
  int n = nt * 16 + li;
  const float* W = (n < 64) ? Wq : ((n < 128) ? Wk : Wv);
  int col = n & 63;
  float sc = (n < 64) ? LOG2E : 1.0f;
  int k0 = ch * 32 + lg * 8;
  short8 hv, lv;
#pragma unroll
  for (int u = 0; u < 8; ++u) {
    float w = W[(k0 + u) * 64 + col] * sc;
    unsigned short h = f2bf(w);
    hv[u] = (short)h;
    lv[u] = (short)f2bf(w - bf2f(h));
  }
  *(short8*)(Wfh + (size_t)id * 8) = hv;
  *(short8*)(Wfl + (size_t)id * 8) = lv;
}

// ---------------------------------------------------------------------------
// proj (r5-proven verbatim): x @ Wf -> Qh/Ql, Kh/Kl, Vt.
// ---------------------------------------------------------------------------
__global__ __launch_bounds__(256) void proj_kernel(
    const float* __restrict__ x,
    const unsigned short* __restrict__ Wfh, const unsigned short* __restrict__ Wfl,
    const float* __restrict__ bq, const float* __restrict__ bk,
    const float* __restrict__ bv,
    unsigned short* __restrict__ Qh, unsigned short* __restrict__ Ql,
    unsigned short* __restrict__ Kh, unsigned short* __restrict__ Kl,
    unsigned short* __restrict__ Vt)
{
  __shared__ __align__(16) char sm[49408];
  const int t = threadIdx.x;
  const int wv = t >> 6, lane = t & 63, li = lane & 15, lg = lane >> 4;
  const int m0 = blockIdx.x * 64;

  f32x4 acc[12];
#pragma unroll
  for (int nt = 0; nt < 12; ++nt) { acc[nt] = (f32x4){0.f,0.f,0.f,0.f}; fence_before_mfma(acc[nt]); }

#pragma unroll 1
  for (int ch = 0; ch < 8; ++ch) {
    if (ch) __syncthreads();
#pragma unroll
    for (int i = 0; i < 3; ++i) {
      int sl = t + i * 256;
      *(uint4*)(sm + sl * 16)         = *(const uint4*)(Wfh + (size_t)ch * 6144 + sl * 8);
      *(uint4*)(sm + 12288 + sl * 16) = *(const uint4*)(Wfl + (size_t)ch * 6144 + sl * 8);
    }
    __syncthreads();
    const float* xp = x + (size_t)(m0 + wv * 16 + li) * 256 + ch * 32 + lg * 8;
    f32x4 xa = *(const f32x4*)xp;
    f32x4 xb = *(const f32x4*)(xp + 4);
    short8 xh, xl;
#pragma unroll
    for (int u = 0; u < 4; ++u) {
      unsigned short h = f2bf(xa[u]);
      xh[u] = (short)h; xl[u] = (short)f2bf(xa[u] - bf2f(h));
      unsigned short h2 = f2bf(xb[u]);
      xh[4 + u] = (short)h2; xl[4 + u] = (short)f2bf(xb[u] - bf2f(h2));
    }
    fence_frag(xh);
    fence_frag(xl);
#pragma unroll
    for (int nt = 0; nt < 12; ++nt) {
      short8 wh = *(const short8*)(sm + (nt * 64 + lg * 16 + li) * 16);
      short8 wl = *(const short8*)(sm + 12288 + (nt * 64 + lg * 16 + li) * 16);
      mfma16(acc[nt], wh, xh);
      mfma16(acc[nt], wh, xl);
      mfma16(acc[nt], wl, xh);
    }
  }
#pragma unroll
  for (int nt = 0; nt < 12; ++nt) fence_after_mfma(acc[nt]);
  __syncthreads();

  float* aL = (float*)(sm + wv * 12352);   // wave-private [16 rows][193 cols]
#pragma unroll
  for (int nt = 0; nt < 12; ++nt)
#pragma unroll
    for (int r = 0; r < 4; ++r)
      aL[li * 193 + nt * 16 + lg * 4 + r] = acc[nt][r];

  const int row = m0 + wv * 16 + li;
  const int b_idx = row >> 12, s0 = row & 4095;
  {
    unsigned int hq[8], lq[8];
#pragma unroll
    for (int c = 0; c < 16; c += 2) {
      float q0 = aL[li * 193 + lg * 16 + c]     + bq[lg * 16 + c] * LOG2E;
      float q1 = aL[li * 193 + lg * 16 + c + 1] + bq[lg * 16 + c + 1] * LOG2E;
      unsigned short h0 = f2bf(q0), h1 = f2bf(q1);
      hq[c >> 1] = (unsigned int)h0 | ((unsigned int)h1 << 16);
      lq[c >> 1] = (unsigned int)f2bf(q0 - bf2f(h0)) | ((unsigned int)f2bf(q1 - bf2f(h1)) << 16);
    }
    size_t o = (size_t)row * 64 + lg * 16;
    *(uint4*)(Qh + o)     = make_uint4(hq[0], hq[1], hq[2], hq[3]);
    *(uint4*)(Qh + o + 8) = make_uint4(hq[4], hq[5], hq[6], hq[7]);
    *(uint4*)(Ql + o)     = make_uint4(lq[0], lq[1], lq[2], lq[3]);
    *(uint4*)(Ql + o + 8) = make_uint4(lq[4], lq[5], lq[6], lq[7]);
  }
  {
    unsigned int hk[8], lk[8];
#pragma unroll
    for (int c = 0; c < 16; c += 2) {
      float k0 = aL[li * 193 + 64 + lg * 16 + c]     + bk[lg * 16 + c];
      float k1 = aL[li * 193 + 64 + lg * 16 + c + 1] + bk[lg * 16 + c + 1];
      unsigned short h0 = f2bf(k0), h1 = f2bf(k1);
      hk[c >> 1] = (unsigned int)h0 | ((unsigned int)h1 << 16);
      lk[c >> 1] = (unsigned int)f2bf(k0 - bf2f(h0)) | ((unsigned int)f2bf(k1 - bf2f(h1)) << 16);
    }
    size_t o = (size_t)row * 64 + lg * 16;
    *(uint4*)(Kh + o)     = make_uint4(hk[0], hk[1], hk[2], hk[3]);
    *(uint4*)(Kh + o + 8) = make_uint4(hk[4], hk[5], hk[6], hk[7]);
    *(uint4*)(Kl + o)     = make_uint4(lk[0], lk[1], lk[2], lk[3]);
    *(uint4*)(Kl + o + 8) = make_uint4(lk[4], lk[5], lk[6], lk[7]);
  }
#pragma unroll
  for (int c = 0; c < 16; ++c) {
    float vv = aL[li * 193 + 128 + lg * 16 + c] + bv[lg * 16 + c];
    Vt[((size_t)b_idx * 64 + lg * 16 + c) * 4096 + s0] = f2bf(vv);
  }
}

// ---------------------------------------------------------------------------
// attn: fused two-pass flash. Grid 512 (XCD-mapped, 2 blocks/CU). Block =
// 32 q-rows (2 q-groups of 16); 4 waves j-split (1024 j each). K/V direct
// global->reg (L2-resident, r6-proven); zero main-loop barriers; volatile
// MFMA chains manually interleaved (4 indep accs round-robin). Pass 1:
// per-row (m,z) -> shfl + LDS combine -> L. Pass 2: bit-identical scores
// (same inlined lambda), p = 2^(s-L) > 2^-12 mask, P via wave-private
// swizzled LDS (r5-proven), PV accumulate; cross-wave O reduce in LDS.
// LDS: P 4wv x 4KB @0 (dead after pass2) | OB [4][32][68]f32 @0 (34816B)
//      stats smm@34816, smz@35328 (512B each). Total 35840.
// ---------------------------------------------------------------------------
__global__ __launch_bounds__(256, 2) void attn_kernel(
    const unsigned short* __restrict__ Qh, const unsigned short* __restrict__ Ql,
    const unsigned short* __restrict__ Kh, const unsigned short* __restrict__ Kl,
    const unsigned short* __restrict__ Vt,
    float* __restrict__ out)
{
  __shared__ __align__(16) char smc[35840];
  const int t = threadIdx.x;
  const int wv = t >> 6, lane = t & 63, li = lane & 15, lg = lane >> 4;
  const int bid = blockIdx.x, g = bid & 7;
  const int b  = g >> 1;                          // 2 XCDs per batch
  const int qt = ((bid >> 3) << 1) | (g & 1);     // 0..127 (32-row q-tiles)
  const int q0 = qt * 32;
  const int sw = li & 7;

  // Q fragments: 2 q-groups x (k-chunks 0,1) hi/lo
  short8 qh[2][2], qlo[2][2];
#pragma unroll
  for (int qg = 0; qg < 2; ++qg) {
    size_t base = ((size_t)(b * 4096 + q0 + qg * 16 + li)) * 64 + lg * 8;
    qh[qg][0]  = *(const short8*)(Qh + base);
    qh[qg][1]  = *(const short8*)(Qh + base + 32);
    qlo[qg][0] = *(const short8*)(Ql + base);
    qlo[qg][1] = *(const short8*)(Ql + base + 32);
  }
  const size_t kB = (size_t)b * 262144;
  const int j0w = wv * 1024;

  // Identical QK sequence for both passes (volatile => fixed issue order).
  // a<qg><sub>: acc for q-group qg, j-subtile sub (rows j0+sub*16..+15).
  auto qk_step = [&](int j0, f32x4& a00, f32x4& a01, f32x4& a10, f32x4& a11) {
    size_t ka = kB + (size_t)(j0 + li) * 64 + lg * 8;
    short8 kh00 = *(const short8*)(Kh + ka);
    short8 kh01 = *(const short8*)(Kh + ka + 32);
    short8 kl00 = *(const short8*)(Kl + ka);
    short8 kl01 = *(const short8*)(Kl + ka + 32);
    short8 kh10 = *(const short8*)(Kh + ka + 1024);
    short8 kh11 = *(const short8*)(Kh + ka + 1056);
    short8 kl10 = *(const short8*)(Kl + ka + 1024);
    short8 kl11 = *(const short8*)(Kl + ka + 1056);
    fence_before_mfma(a00); fence_before_mfma(a01);
    fence_before_mfma(a10); fence_before_mfma(a11);
    // round-robin over 4 independent chains; 6 steps each
    mfma16(a00, kh00, qh[0][0]);  mfma16(a01, kh10, qh[0][0]);
    mfma16(a10, kh00, qh[1][0]);  mfma16(a11, kh10, qh[1][0]);
    mfma16(a00, kh00, qlo[0][0]); mfma16(a01, kh10, qlo[0][0]);
    mfma16(a10, kh00, qlo[1][0]); mfma16(a11, kh10, qlo[1][0]);
    mfma16(a00, kl00, qh[0][0]);  mfma16(a01, kl10, qh[0][0]);
    mfma16(a10, kl00, qh[1][0]);  mfma16(a11, kl10, qh[1][0]);
    mfma16(a00, kh01, qh[0][1]);  mfma16(a01, kh11, qh[0][1]);
    mfma16(a10, kh01, qh[1][1]);  mfma16(a11, kh11, qh[1][1]);
    mfma16(a00, kh01, qlo[0][1]); mfma16(a01, kh11, qlo[0][1]);
    mfma16(a10, kh01, qlo[1][1]); mfma16(a11, kh11, qlo[1][1]);
    mfma16(a00, kl01, qh[0][1]);  mfma16(a01, kl11, qh[0][1]);
    mfma16(a10, kl01, qh[1][1]);  mfma16(a11, kl11, qh[1][1]);
    fence_after_mfma(a00); fence_after_mfma(a01);
    fence_after_mfma(a10); fence_after_mfma(a11);
  };

  // ===== pass 1: per-row (m, z) over this wave's j-quarter =====
  float m0 = -3.0e38f, z0 = 0.0f, m1 = -3.0e38f, z1 = 0.0f;
#pragma unroll 1
  for (int js = 0; js < 32; ++js) {
    f32x4 a00 = {0.f,0.f,0.f,0.f}, a01 = {0.f,0.f,0.f,0.f};
    f32x4 a10 = {0.f,0.f,0.f,0.f}, a11 = {0.f,0.f,0.f,0.f};
    qk_step(j0w + js * 32, a00, a01, a10, a11);
    {
      float mx = fmaxf(fmaxf(fmaxf(a00[0], a00[1]), fmaxf(a00[2], a00[3])),
                       fmaxf(fmaxf(a01[0], a01[1]), fmaxf(a01[2], a01[3])));
      float nm = fmaxf(m0, mx);
      z0 = z0 * __builtin_exp2f(m0 - nm)
         + __builtin_exp2f(a00[0] - nm) + __builtin_exp2f(a00[1] - nm)
         + __builtin_exp2f(a00[2] - nm) + __builtin_exp2f(a00[3] - nm)
         + __builtin_exp2f(a01[0] - nm) + __builtin_exp2f(a01[1] - nm)
         + __builtin_exp2f(a01[2] - nm) + __builtin_exp2f(a01[3] - nm);
      m0 = nm;
    }
    {
      float mx = fmaxf(fmaxf(fmaxf(a10[0], a10[1]), fmaxf(a10[2], a10[3])),
                       fmaxf(fmaxf(a11[0], a11[1]), fmaxf(a11[2], a11[3])));
      float nm = fmaxf(m1, mx);
      z1 = z1 * __builtin_exp2f(m1 - nm)
         + __builtin_exp2f(a10[0] - nm) + __builtin_exp2f(a10[1] - nm)
         + __builtin_exp2f(a10[2] - nm) + __builtin_exp2f(a10[3] - nm)
         + __builtin_exp2f(a11[0] - nm) + __builtin_exp2f(a11[1] - nm)
         + __builtin_exp2f(a11[2] - nm) + __builtin_exp2f(a11[3] - nm);
      m1 = nm;
    }
  }
  // combine lg-groups (lanes li, li+16, li+32, li+48 share q-row)
#pragma unroll
  for (int off = 16; off < 64; off <<= 1) {
    float om = __shfl_xor(m0, off, 64), oz = __shfl_xor(z0, off, 64);
    float nm = fmaxf(m0, om);
    z0 = z0 * __builtin_exp2f(m0 - nm) + oz * __builtin_exp2f(om - nm);
    m0 = nm;
    om = __shfl_xor(m1, off, 64); oz = __shfl_xor(z1, off, 64);
    nm = fmaxf(m1, om);
    z1 = z1 * __builtin_exp2f(m1 - nm) + oz * __builtin_exp2f(om - nm);
    m1 = nm;
  }
  float* smm = (float*)(smc + 34816);
  float* smz = (float*)(smc + 35328);
  if (lane < 16) {
    smm[wv * 32 + li]      = m0;  smz[wv * 32 + li]      = z0;
    smm[wv * 32 + 16 + li] = m1;  smz[wv * 32 + 16 + li] = z1;
  }
  __syncthreads();
  if (t < 32) {
    float M = smm[t], Z = smz[t];
#pragma unroll
    for (int w2 = 1; w2 < 4; ++w2) {
      float om = smm[w2 * 32 + t], oz = smz[w2 * 32 + t];
      float nm = fmaxf(M, om);
      Z = Z * __builtin_exp2f(M - nm) + oz * __builtin_exp2f(om - nm);
      M = nm;
    }
    smm[t] = (Z > 0.0f) ? (M + __builtin_log2f(Z)) : M;
  }
  __syncthreads();
  const float Lq0 = smm[li], Lq1 = smm[16 + li];

  // ===== pass 2: masked PV over the same j-quarter =====
  f32x4 o00={0.f,0.f,0.f,0.f}, o01={0.f,0.f,0.f,0.f}, o02={0.f,0.f,0.f,0.f}, o03={0.f,0.f,0.f,0.f};
  f32x4 o10={0.f,0.f,0.f,0.f}, o11={0.f,0.f,0.f,0.f}, o12={0.f,0.f,0.f,0.f}, o13={0.f,0.f,0.f,0.f};
  fence_before_mfma(o00); fence_before_mfma(o01); fence_before_mfma(o02); fence_before_mfma(o03);
  fence_before_mfma(o10); fence_before_mfma(o11); fence_before_mfma(o12); fence_before_mfma(o13);

  const int pb0 = wv * 4096 + li * 128;   // wave-private P, q-group 0
  const int pb1 = pb0 + 2048;             // q-group 1
  const int hb  = (lg & 1) * 8;
  const int oct0 = (lg >> 1);             // sub 0
  const int oct1 = 2 + (lg >> 1);         // sub 1

#pragma unroll 1
  for (int js = 0; js < 32; ++js) {
    const int j0 = j0w + js * 32;
    f32x4 a00 = {0.f,0.f,0.f,0.f}, a01 = {0.f,0.f,0.f,0.f};
    f32x4 a10 = {0.f,0.f,0.f,0.f}, a11 = {0.f,0.f,0.f,0.f};
    qk_step(j0, a00, a01, a10, a11);
    // masked P -> wave-private swizzled LDS (r5 pattern, subtiles 0..1)
    {
      float p0 = __builtin_exp2f(a00[0] - Lq0); p0 = (p0 > MASK_THR) ? p0 : 0.0f;
      float p1 = __builtin_exp2f(a00[1] - Lq0); p1 = (p1 > MASK_THR) ? p1 : 0.0f;
      float p2 = __builtin_exp2f(a00[2] - Lq0); p2 = (p2 > MASK_THR) ? p2 : 0.0f;
      float p3 = __builtin_exp2f(a00[3] - Lq0); p3 = (p3 > MASK_THR) ? p3 : 0.0f;
      uint2 pw;
      pw.x = (unsigned int)f2bf(p0) | ((unsigned int)f2bf(p1) << 16);
      pw.y = (unsigned int)f2bf(p2) | ((unsigned int)f2bf(p3) << 16);
      *(uint2*)(smc + pb0 + ((oct0 ^ sw) << 4) + hb) = pw;
      p0 = __builtin_exp2f(a01[0] - Lq0); p0 = (p0 > MASK_THR) ? p0 : 0.0f;
      p1 = __builtin_exp2f(a01[1] - Lq0); p1 = (p1 > MASK_THR) ? p1 : 0.0f;
      p2 = __builtin_exp2f(a01[2] - Lq0); p2 = (p2 > MASK_THR) ? p2 : 0.0f;
      p3 = __builtin_exp2f(a01[3] - Lq0); p3 = (p3 > MASK_THR) ? p3 : 0.0f;
      pw.x = (unsigned int)f2bf(p0) | ((unsigned int)f2bf(p1) << 16);
      pw.y = (unsigned int)f2bf(p2) | ((unsigned int)f2bf(p3) << 16);
      *(uint2*)(smc + pb0 + ((oct1 ^ sw) << 4) + hb) = pw;
      p0 = __builtin_exp2f(a10[0] - Lq1); p0 = (p0 > MASK_THR) ? p0 : 0.0f;
      p1 = __builtin_exp2f(a10[1] - Lq1); p1 = (p1 > MASK_THR) ? p1 : 0.0f;
      p2 = __builtin_exp2f(a10[2] - Lq1); p2 = (p2 > MASK_THR) ? p2 : 0.0f;
      p3 = __builtin_exp2f(a10[3] - Lq1); p3 = (p3 > MASK_THR) ? p3 : 0.0f;
      pw.x = (unsigned int)f2bf(p0) | ((unsigned int)f2bf(p1) << 16);
      pw.y = (unsigned int)f2bf(p2) | ((unsigned int)f2bf(p3) << 16);
      *(uint2*)(smc + pb1 + ((oct0 ^ sw) << 4) + hb) = pw;
      p0 = __builtin_exp2f(a11[0] - Lq1); p0 = (p0 > MASK_THR) ? p0 : 0.0f;
      p1 = __builtin_exp2f(a11[1] - Lq1); p1 = (p1 > MASK_THR) ? p1 : 0.0f;
      p2 = __builtin_exp2f(a11[2] - Lq1); p2 = (p2 > MASK_THR) ? p2 : 0.0f;
      p3 = __builtin_exp2f(a11[3] - Lq1); p3 = (p3 > MASK_THR) ? p3 : 0.0f;
      pw.x = (unsigned int)f2bf(p0) | ((unsigned int)f2bf(p1) << 16);
      pw.y = (unsigned int)f2bf(p2) | ((unsigned int)f2bf(p3) << 16);
      *(uint2*)(smc + pb1 + ((oct1 ^ sw) << 4) + hb) = pw;
    }
    short8 pa0 = *(const short8*)(smc + pb0 + ((lg ^ sw) << 4));
    short8 pa1 = *(const short8*)(smc + pb1 + ((lg ^ sw) << 4));
    // V fragments direct from global (B-operand), d-groups 0..3
    size_t va = ((size_t)b * 64 + li) * 4096 + j0 + lg * 8;
    short8 vb0 = *(const short8*)(Vt + va);
    short8 vb1 = *(const short8*)(Vt + va + 65536);
    short8 vb2 = *(const short8*)(Vt + va + 131072);
    short8 vb3 = *(const short8*)(Vt + va + 196608);
    mfma16(o00, pa0, vb0); mfma16(o10, pa1, vb0);
    mfma16(o01, pa0, vb1); mfma16(o11, pa1, vb1);
    mfma16(o02, pa0, vb2); mfma16(o12, pa1, vb2);
    mfma16(o03, pa0, vb3); mfma16(o13, pa1, vb3);
  }
  fence_after_mfma(o00); fence_after_mfma(o01); fence_after_mfma(o02); fence_after_mfma(o03);
  fence_after_mfma(o10); fence_after_mfma(o11); fence_after_mfma(o12); fence_after_mfma(o13);

  // cross-wave O reduction (OB overlaps P region -> barrier first)
  __syncthreads();
  float* ob = (float*)smc;   // [4 wv][32 q][68] f32
#pragma unroll
  for (int r = 0; r < 4; ++r) {
    ob[(wv * 32 +      lg * 4 + r) * 68 +  0 + li] = o00[r];
    ob[(wv * 32 +      lg * 4 + r) * 68 + 16 + li] = o01[r];
    ob[(wv * 32 +      lg * 4 + r) * 68 + 32 + li] = o02[r];
    ob[(wv * 32 +      lg * 4 + r) * 68 + 48 + li] = o03[r];
    ob[(wv * 32 + 16 + lg * 4 + r) * 68 +  0 + li] = o10[r];
    ob[(wv * 32 + 16 + lg * 4 + r) * 68 + 16 + li] = o11[r];
    ob[(wv * 32 + 16 + lg * 4 + r) * 68 + 32 + li] = o12[r];
    ob[(wv * 32 + 16 + lg * 4 + r) * 68 + 48 + li] = o13[r];
  }
  __syncthreads();
  {
    const int q = t >> 3, d8 = (t & 7) * 8;
    f32x4 s0 = {0.f,0.f,0.f,0.f}, s1 = {0.f,0.f,0.f,0.f};
#pragma unroll
    for (int w2 = 0; w2 < 4; ++w2) {
      const float* row = ob + (w2 * 32 + q) * 68 + d8;
      s0 += *(const f32x4*)(row);
      s1 += *(const f32x4*)(row + 4);
    }
    float* op = out + ((size_t)b * 4096 + q0 + q) * 64 + d8;
    *(f32x4*)(op)     = s0;
    *(f32x4*)(op + 4) = s1;
  }
}

extern "C" void kernel_launch(void* const* d_in, const int* in_sizes, int n_in,
                              void* d_out, int out_size, void* d_ws, size_t ws_size,
                              hipStream_t stream) {
  (void)in_sizes; (void)n_in; (void)out_size; (void)ws_size;
  const float* x  = (const float*)d_in[0];
  const float* Wq = (const float*)d_in[1];
  const float* bq = (const float*)d_in[2];
  const float* Wk = (const float*)d_in[3];
  const float* bk = (const float*)d_in[4];
  const float* Wv = (const float*)d_in[5];
  const float* bv = (const float*)d_in[6];
  float* out = (float*)d_out;

  char* wsb = (char*)d_ws;
  unsigned short* Qh  = (unsigned short*)(wsb);
  unsigned short* Ql  = (unsigned short*)(wsb + 2097152);
  unsigned short* Kh  = (unsigned short*)(wsb + 4194304);
  unsigned short* Kl  = (unsigned short*)(wsb + 6291456);
  unsigned short* Vt  = (unsigned short*)(wsb + 8388608);
  unsigned short* Wfh = (unsigned short*)(wsb + 10485760);
  unsigned short* Wfl = (unsigned short*)(wsb + 10584064);

  prep_w_kernel<<<dim3(24), dim3(256), 0, stream>>>(Wq, Wk, Wv, Wfh, Wfl);
  proj_kernel<<<dim3(256), dim3(256), 0, stream>>>(
      x, Wfh, Wfl, bq, bk, bv, Qh, Ql, Kh, Kl, Vt);
  attn_kernel<<<dim3(512), dim3(256), 0, stream>>>(Qh, Ql, Kh, Kl, Vt, out);
}